// Round 11
// baseline (341.526 us; speedup 1.0000x reference)
//
#include <hip/hip_runtime.h>

#define NN 50000
#define NE 800000
#define BSHIFT 9
#define NB_BUCKET ((NN + 511) >> BSHIFT)       // 98
#define BCAP 16384                             // slots per bucket region
#define EPB 2048                               // edges per binA block
#define NBLK_E ((NE + EPB - 1) / EPB)          // 391

// setup kernel block partition
#define CVT_BLKS 6250                          // NN*128/4/256 exactly
#define PREP_BLKS 32
#define SETUP_GRID (CVT_BLKS + PREP_BLKS + 1)

#define LROW 136                               // LDS row stride (bf16) -> uniform bank groups

typedef short short8 __attribute__((ext_vector_type(8)));
typedef short short4v __attribute__((ext_vector_type(4)));
typedef float f32x4 __attribute__((ext_vector_type(4)));

__device__ inline unsigned short bf16_rne(float f) {
    unsigned u = __float_as_uint(f);
    unsigned r = (u + 0x7fffu + ((u >> 16) & 1u)) >> 16;
    return (unsigned short)r;
}
__device__ inline float bf16_to_f32(unsigned short h) {
    return __uint_as_float((unsigned)h << 16);
}

// ---- fused setup: cvt x->bf16 | weight prep | zero bucket cursors ----------
__global__ __launch_bounds__(256) void setup_kernel(const float* __restrict__ x,
                                                    unsigned short* __restrict__ xb,
                                                    const float* __restrict__ W0,
                                                    const float* __restrict__ W1,
                                                    const float* __restrict__ W2,
                                                    const float* __restrict__ W3,
                                                    short* __restrict__ wf,
                                                    int* __restrict__ cursor0) {
    int b = blockIdx.x;
    if (b < CVT_BLKS) {                       // x -> bf16 (one float4/thread, exact)
        int i = b * 256 + threadIdx.x;
        float4 v = ((const float4*)x)[i];
        short4v r;
        r[0] = (short)bf16_rne(v.x);
        r[1] = (short)bf16_rne(v.y);
        r[2] = (short)bf16_rne(v.z);
        r[3] = (short)bf16_rne(v.w);
        ((short4v*)xb)[i] = r;
    } else if (b < CVT_BLKS + PREP_BLKS) {    // weight split+fragment reorder
        int t = (b - CVT_BLKS) * 256 + threadIdx.x;   // 0..8191
        int mat = t >> 11;
        const float* W = (mat == 0) ? W0 : (mat == 1) ? W1 : (mat == 2) ? W2 : W3;
        short* out = wf + (size_t)mat * 32768;
        int r = t & 2047;
        int nt = r >> 8;
        int kc = (r >> 6) & 3;
        int lane = r & 63;
        int n = nt * 16 + (lane & 15);
        int kbase = kc * 32 + ((lane >> 4) << 3);
        short8 vh, vl;
#pragma unroll
        for (int j = 0; j < 8; ++j) {
            float w = W[(size_t)(kbase + j) * 128 + n];
            unsigned short h = bf16_rne(w);
            unsigned short l = bf16_rne(w - bf16_to_f32(h));
            vh[j] = (short)h;
            vl[j] = (short)l;
        }
        size_t o = ((((size_t)nt * 4 + kc) * 2) * 64 + lane) * 8;
        *(short8*)(out + o) = vh;
        *(short8*)(out + o + 512) = vl;
    } else {                                  // zero bucket cursors
        if (threadIdx.x < NB_BUCKET) cursor0[threadIdx.x] = 0;
    }
}

// ---- phase A: bin edges into fixed bucket regions, packed (dl<<16)|src -----
__global__ __launch_bounds__(256) void binA_kernel(const int* __restrict__ src,
                                                   const int* __restrict__ dst,
                                                   int* __restrict__ cursor0,
                                                   unsigned* __restrict__ packed, int ne) {
    __shared__ int cnt[NB_BUCKET];
    __shared__ int gstart[NB_BUCKET];
    __shared__ int cur[NB_BUCKET];
    int t = threadIdx.x;
    if (t < NB_BUCKET) cnt[t] = 0;
    __syncthreads();
    int base = blockIdx.x * EPB + t * 8;
    int s[8], d[8];
    int m = 0;
    if (base + 8 <= ne) {
        *(int4*)&s[0] = *(const int4*)(src + base);
        *(int4*)&s[4] = *(const int4*)(src + base + 4);
        *(int4*)&d[0] = *(const int4*)(dst + base);
        *(int4*)&d[4] = *(const int4*)(dst + base + 4);
        m = 8;
    } else if (base < ne) {
        m = ne - base;
        for (int i = 0; i < m; ++i) { s[i] = src[base + i]; d[i] = dst[base + i]; }
    }
    for (int i = 0; i < m; ++i) atomicAdd(&cnt[d[i] >> BSHIFT], 1);
    __syncthreads();
    if (t < NB_BUCKET) {
        gstart[t] = t * BCAP + atomicAdd(&cursor0[t], cnt[t]);
        cur[t] = 0;
    }
    __syncthreads();
    for (int i = 0; i < m; ++i) {
        int b = d[i] >> BSHIFT;
        int l = atomicAdd(&cur[b], 1);
        packed[gstart[b] + l] = ((unsigned)(d[i] & 511) << 16) | (unsigned)s[i];
    }
}

// ---- phase B: one block per bucket; LDS deg + wave-scan -> row_ptr/col -----
__global__ __launch_bounds__(512) void binB_kernel(const unsigned* __restrict__ packed,
                                                   const int* __restrict__ cursor0,
                                                   int* __restrict__ row_ptr,
                                                   float* __restrict__ inv_deg,
                                                   int* __restrict__ col, int n, int ne) {
    __shared__ int sdeg[512];
    __shared__ int scur[512];
    __shared__ int scnt[NB_BUCKET];
    __shared__ int sebeg[NB_BUCKET];
    __shared__ int swv[8];
    int b = blockIdx.x, t = threadIdx.x;
    int lane = t & 63, wid = t >> 6;
    if (t < NB_BUCKET) scnt[t] = cursor0[t];
    sdeg[t] = 0;
    __syncthreads();
    if (t == 0) {                 // serial 98-scan (cheap, per-block)
        int run = 0;
        for (int i = 0; i < NB_BUCKET; ++i) { sebeg[i] = run; run += scnt[i]; }
    }
    __syncthreads();
    int ebeg = sebeg[b];
    int cntE = scnt[b];
    const unsigned* pk = packed + (size_t)b * BCAP;
    for (int e = t; e < cntE; e += 512) atomicAdd(&sdeg[pk[e] >> 16], 1);
    __syncthreads();
    int v = sdeg[t];
    int incl = v;                 // wave-level inclusive scan
#pragma unroll
    for (int d = 1; d < 64; d <<= 1) {
        int u = __shfl_up(incl, d, 64);
        if (lane >= d) incl += u;
    }
    if (lane == 63) swv[wid] = incl;
    __syncthreads();
    int wbase = 0;
    for (int i = 0; i < 8; ++i) wbase += (i < wid) ? swv[i] : 0;
    int excl = wbase + incl - v;
    scur[t] = excl;
    int node = (b << BSHIFT) + t;
    if (node < n) {
        row_ptr[node] = ebeg + excl;
        inv_deg[node] = 1.0f / (float)(v > 0 ? v : 1);
    }
    if (b == 0 && t == 0) row_ptr[n] = ne;
    __syncthreads();
    for (int e = t; e < cntE; e += 512) {
        unsigned w = pk[e];
        int dl = w >> 16;
        int pos = ebeg + atomicAdd(&scur[dl], 1);
        col[pos] = (int)(w & 0xffffu);
    }
}

// ---- fused layer: mean-agg (per-wave, into LDS) + dual GEMM MFMA (+opt FC) --
// Each wave owns 16 nodes: aggregates them into its private LDS tile, then
// computes D = Wl^T@agg^T + Wr^T@root^T via swapped-operand MFMA (W as A,
// features as B): C/D col = node (lane&15), row = hid (quad*4+reg) -> each
// lane's 4 acc regs are 4 consecutive hids -> 8B coalesced stores.
__global__ __launch_bounds__(256) void fused_layer(const unsigned short* __restrict__ hb,
                                                   const unsigned short* __restrict__ rootb,
                                                   const int* __restrict__ row_ptr,
                                                   const int* __restrict__ col,
                                                   const float* __restrict__ inv_deg,
                                                   const short* __restrict__ Wf0,
                                                   const short* __restrict__ Wf1,
                                                   const float* __restrict__ bias,
                                                   unsigned short* __restrict__ outb,
                                                   const float* __restrict__ Wfc,
                                                   const float* __restrict__ bfc,
                                                   float* __restrict__ fcout, int n) {
    __shared__ unsigned short At[4][16 * LROW];
    int tid = threadIdx.x;
    int w = tid >> 6, lane = tid & 63;
    int slot = lane >> 4, sub = lane & 15;      // agg roles; gemm: quad=slot, m16=sub
    int nbase = blockIdx.x * 64 + w * 16;
    unsigned short* lds = &At[w][0];

    // ---- phase 1: aggregate this wave's 16 nodes ----
    for (int i = 0; i < 16; ++i) {
        int node = nbase + i;
        float acc[8];
#pragma unroll
        for (int j = 0; j < 8; ++j) acc[j] = 0.f;
        if (node < n) {
            int beg = row_ptr[node], end = row_ptr[node + 1];
            const unsigned short* base = hb + (sub << 3);
            int e = beg + slot;
            for (; e + 4 < end; e += 8) {
                int j0 = col[e];
                int j1 = col[e + 4];
                uint4 v0 = *(const uint4*)(base + ((size_t)j0 << 7));
                uint4 v1 = *(const uint4*)(base + ((size_t)j1 << 7));
                unsigned w0[4] = {v0.x, v0.y, v0.z, v0.w};
                unsigned w1[4] = {v1.x, v1.y, v1.z, v1.w};
#pragma unroll
                for (int d = 0; d < 4; ++d) {
                    acc[2 * d + 0] += __uint_as_float(w0[d] << 16);
                    acc[2 * d + 1] += __uint_as_float(w0[d] & 0xffff0000u);
                    acc[2 * d + 0] += __uint_as_float(w1[d] << 16);
                    acc[2 * d + 1] += __uint_as_float(w1[d] & 0xffff0000u);
                }
            }
            if (e < end) {
                int j0 = col[e];
                uint4 v0 = *(const uint4*)(base + ((size_t)j0 << 7));
                unsigned w0[4] = {v0.x, v0.y, v0.z, v0.w};
#pragma unroll
                for (int d = 0; d < 4; ++d) {
                    acc[2 * d + 0] += __uint_as_float(w0[d] << 16);
                    acc[2 * d + 1] += __uint_as_float(w0[d] & 0xffff0000u);
                }
            }
        }
#pragma unroll
        for (int j = 0; j < 8; ++j) {
            acc[j] += __shfl_xor(acc[j], 16, 64);
            acc[j] += __shfl_xor(acc[j], 32, 64);
        }
        if (slot == 0) {
            float s = (node < n) ? inv_deg[node] : 0.f;
            short8 o;
#pragma unroll
            for (int j = 0; j < 8; ++j) o[j] = (short)bf16_rne(acc[j] * s);
            *(short8*)(lds + i * LROW + sub * 8) = o;
        }
    }
    __syncthreads();   // cheap safety barrier (per-wave data; one barrier total)

    // ---- phase 2: dual GEMM (swapped operands: W as A, features as B) ----
    int quad = slot, m16 = sub;
    f32x4 acc2[8];
#pragma unroll
    for (int nt = 0; nt < 8; ++nt) acc2[nt] = (f32x4){0.f, 0.f, 0.f, 0.f};

    int rrow = nbase + m16;
    if (rrow > n - 1) rrow = n - 1;
    const unsigned short* rp = rootb + ((size_t)rrow << 7) + (quad << 3);
#pragma unroll
    for (int kc = 0; kc < 4; ++kc) {
        short8 aA = *(const short8*)(lds + m16 * LROW + (quad + 4 * kc) * 8);
        short8 aR = *(const short8*)(rp + kc * 32);
        const short* wp0 = Wf0 + ((size_t)kc * 2 * 64 + lane) * 8;
        const short* wp1 = Wf1 + ((size_t)kc * 2 * 64 + lane) * 8;
#pragma unroll
        for (int nt = 0; nt < 8; ++nt) {
            short8 bh0 = *(const short8*)(wp0 + (size_t)nt * 4096);
            short8 bl0 = *(const short8*)(wp0 + (size_t)nt * 4096 + 512);
            short8 bh1 = *(const short8*)(wp1 + (size_t)nt * 4096);
            short8 bl1 = *(const short8*)(wp1 + (size_t)nt * 4096 + 512);
            acc2[nt] = __builtin_amdgcn_mfma_f32_16x16x32_bf16(bh0, aA, acc2[nt], 0, 0, 0);
            acc2[nt] = __builtin_amdgcn_mfma_f32_16x16x32_bf16(bl0, aA, acc2[nt], 0, 0, 0);
            acc2[nt] = __builtin_amdgcn_mfma_f32_16x16x32_bf16(bh1, aR, acc2[nt], 0, 0, 0);
            acc2[nt] = __builtin_amdgcn_mfma_f32_16x16x32_bf16(bl1, aR, acc2[nt], 0, 0, 0);
        }
    }

    // ---- epilogue (col = node m16, row = hid nt*16 + quad*4 + r) ----
    int onode = nbase + m16;
    if (outb) {
        if (onode < n) {
            unsigned short* op = outb + ((size_t)onode << 7) + (quad << 2);
#pragma unroll
            for (int nt = 0; nt < 8; ++nt) {
                float4 bs = *(const float4*)(bias + nt * 16 + (quad << 2));
                short4v o;
                o[0] = (short)bf16_rne(fmaxf(acc2[nt][0] + bs.x, 0.f));
                o[1] = (short)bf16_rne(fmaxf(acc2[nt][1] + bs.y, 0.f));
                o[2] = (short)bf16_rne(fmaxf(acc2[nt][2] + bs.z, 0.f));
                o[3] = (short)bf16_rne(fmaxf(acc2[nt][3] + bs.w, 0.f));
                *(short4v*)(op + nt * 16) = o;
            }
        }
    } else {
        // fused FC: lane holds 32 hids of node m16; reduce over quad groups
        float p0 = 0.f, p1 = 0.f;
#pragma unroll
        for (int nt = 0; nt < 8; ++nt) {
            float4 bs = *(const float4*)(bias + nt * 16 + (quad << 2));
            float bv[4] = {bs.x, bs.y, bs.z, bs.w};
#pragma unroll
            for (int r = 0; r < 4; ++r) {
                float v = fmaxf(acc2[nt][r] + bv[r], 0.f);
                int hid = nt * 16 + (quad << 2) + r;
                float2 wv = *(const float2*)(Wfc + 2 * hid);
                p0 += v * wv.x;
                p1 += v * wv.y;
            }
        }
        p0 += __shfl_xor(p0, 16, 64);
        p0 += __shfl_xor(p0, 32, 64);
        p1 += __shfl_xor(p1, 16, 64);
        p1 += __shfl_xor(p1, 32, 64);
        if (quad == 0 && onode < n) {
            float2 o;
            o.x = p0 + bfc[0];
            o.y = p1 + bfc[1];
            *(float2*)(fcout + 2 * (size_t)onode) = o;
        }
    }
}

extern "C" void kernel_launch(void* const* d_in, const int* in_sizes, int n_in,
                              void* d_out, int out_size, void* d_ws, size_t ws_size,
                              hipStream_t stream) {
    const float* x   = (const float*)d_in[0];
    const int* edge  = (const int*)d_in[1];
    const float* W1l = (const float*)d_in[2];
    const float* W1r = (const float*)d_in[3];
    const float* b1  = (const float*)d_in[4];
    const float* W2l = (const float*)d_in[5];
    const float* W2r = (const float*)d_in[6];
    const float* b2  = (const float*)d_in[7];
    const float* Wfc = (const float*)d_in[8];
    const float* bfc = (const float*)d_in[9];
    float* out = (float*)d_out;

    const int n = NN, ne = NE;
    const int* src = edge;        // edge_index[0]
    const int* dst = edge + ne;   // edge_index[1]

    char* ws = (char*)d_ws;
    size_t off = 0;
    auto alloc = [&](size_t bytes) -> char* {
        char* p = ws + off;
        off = (off + bytes + 511) & ~(size_t)511;
        return p;
    };
    int* row_ptr     = (int*)alloc((size_t)(n + 1) * 4);
    float* invdeg    = (float*)alloc((size_t)n * 4);
    int* cursor0     = (int*)alloc((size_t)NB_BUCKET * 4);
    short* wf        = (short*)alloc((size_t)4 * 32768 * 2);
    unsigned* packed = (unsigned*)alloc((size_t)NB_BUCKET * BCAP * 4);
    int* col         = (int*)alloc((size_t)ne * 4);
    unsigned short* xb  = (unsigned short*)alloc((size_t)n * 128 * 2);
    unsigned short* h1b = (unsigned short*)alloc((size_t)n * 128 * 2);
    (void)ws_size; (void)in_sizes; (void)n_in; (void)out_size;

    setup_kernel<<<SETUP_GRID, 256, 0, stream>>>(x, xb, W1l, W1r, W2l, W2r, wf, cursor0);
    binA_kernel<<<NBLK_E, 256, 0, stream>>>(src, dst, cursor0, packed, ne);
    binB_kernel<<<NB_BUCKET, 512, 0, stream>>>(packed, cursor0, row_ptr, invdeg, col, n, ne);

    fused_layer<<<(n + 63) / 64, 256, 0, stream>>>(xb, xb, row_ptr, col, invdeg,
                                                   wf, wf + 32768, b1, h1b,
                                                   (const float*)0, (const float*)0, (float*)0, n);
    fused_layer<<<(n + 63) / 64, 256, 0, stream>>>(h1b, h1b, row_ptr, col, invdeg,
                                                   wf + 2 * 32768, wf + 3 * 32768, b2,
                                                   (unsigned short*)0, Wfc, bfc, out, n);
}

// Round 12
// 230.077 us; speedup vs baseline: 1.4844x; 1.4844x over previous
//
#include <hip/hip_runtime.h>

#define NN 50000
#define NE 800000
#define BSHIFT 9
#define NB_BUCKET ((NN + 511) >> BSHIFT)       // 98
#define BCAP 16384                             // slots per bucket region
#define EPB 2048                               // edges per binA block
#define NBLK_E ((NE + EPB - 1) / EPB)          // 391

// setup kernel block partition
#define CVT_BLKS 6250                          // NN*128/4/256 exactly
#define PREP_BLKS 32
#define SETUP_GRID (CVT_BLKS + PREP_BLKS + 1)

typedef short short8 __attribute__((ext_vector_type(8)));
typedef short short4v __attribute__((ext_vector_type(4)));
typedef float f32x4 __attribute__((ext_vector_type(4)));

__device__ inline unsigned short bf16_rne(float f) {
    unsigned u = __float_as_uint(f);
    unsigned r = (u + 0x7fffu + ((u >> 16) & 1u)) >> 16;
    return (unsigned short)r;
}
__device__ inline float bf16_to_f32(unsigned short h) {
    return __uint_as_float((unsigned)h << 16);
}

// ---- fused setup: cvt x->bf16 | weight prep | zero bucket cursors ----------
__global__ __launch_bounds__(256) void setup_kernel(const float* __restrict__ x,
                                                    unsigned short* __restrict__ xb,
                                                    const float* __restrict__ W0,
                                                    const float* __restrict__ W1,
                                                    const float* __restrict__ W2,
                                                    const float* __restrict__ W3,
                                                    short* __restrict__ wf,
                                                    int* __restrict__ cursor0) {
    int b = blockIdx.x;
    if (b < CVT_BLKS) {                       // x -> bf16 (one float4/thread, exact)
        int i = b * 256 + threadIdx.x;
        float4 v = ((const float4*)x)[i];
        short4v r;
        r[0] = (short)bf16_rne(v.x);
        r[1] = (short)bf16_rne(v.y);
        r[2] = (short)bf16_rne(v.z);
        r[3] = (short)bf16_rne(v.w);
        ((short4v*)xb)[i] = r;
    } else if (b < CVT_BLKS + PREP_BLKS) {    // weight split+fragment reorder
        int t = (b - CVT_BLKS) * 256 + threadIdx.x;   // 0..8191
        int mat = t >> 11;
        const float* W = (mat == 0) ? W0 : (mat == 1) ? W1 : (mat == 2) ? W2 : W3;
        short* out = wf + (size_t)mat * 32768;
        int r = t & 2047;
        int nt = r >> 8;
        int kc = (r >> 6) & 3;
        int lane = r & 63;
        int n = nt * 16 + (lane & 15);
        int kbase = kc * 32 + ((lane >> 4) << 3);
        short8 vh, vl;
#pragma unroll
        for (int j = 0; j < 8; ++j) {
            float w = W[(size_t)(kbase + j) * 128 + n];
            unsigned short h = bf16_rne(w);
            unsigned short l = bf16_rne(w - bf16_to_f32(h));
            vh[j] = (short)h;
            vl[j] = (short)l;
        }
        size_t o = ((((size_t)nt * 4 + kc) * 2) * 64 + lane) * 8;
        *(short8*)(out + o) = vh;
        *(short8*)(out + o + 512) = vl;
    } else {                                  // zero bucket cursors
        if (threadIdx.x < NB_BUCKET) cursor0[threadIdx.x] = 0;
    }
}

// ---- phase A: bin edges into fixed bucket regions, packed (dl<<16)|src -----
__global__ __launch_bounds__(256) void binA_kernel(const int* __restrict__ src,
                                                   const int* __restrict__ dst,
                                                   int* __restrict__ cursor0,
                                                   unsigned* __restrict__ packed, int ne) {
    __shared__ int cnt[NB_BUCKET];
    __shared__ int gstart[NB_BUCKET];
    __shared__ int cur[NB_BUCKET];
    int t = threadIdx.x;
    if (t < NB_BUCKET) cnt[t] = 0;
    __syncthreads();
    int base = blockIdx.x * EPB + t * 8;
    int s[8], d[8];
    int m = 0;
    if (base + 8 <= ne) {
        *(int4*)&s[0] = *(const int4*)(src + base);
        *(int4*)&s[4] = *(const int4*)(src + base + 4);
        *(int4*)&d[0] = *(const int4*)(dst + base);
        *(int4*)&d[4] = *(const int4*)(dst + base + 4);
        m = 8;
    } else if (base < ne) {
        m = ne - base;
        for (int i = 0; i < m; ++i) { s[i] = src[base + i]; d[i] = dst[base + i]; }
    }
    for (int i = 0; i < m; ++i) atomicAdd(&cnt[d[i] >> BSHIFT], 1);
    __syncthreads();
    if (t < NB_BUCKET) {
        gstart[t] = t * BCAP + atomicAdd(&cursor0[t], cnt[t]);
        cur[t] = 0;
    }
    __syncthreads();
    for (int i = 0; i < m; ++i) {
        int b = d[i] >> BSHIFT;
        int l = atomicAdd(&cur[b], 1);
        packed[gstart[b] + l] = ((unsigned)(d[i] & 511) << 16) | (unsigned)s[i];
    }
}

// ---- phase B: one block per bucket; LDS deg + wave-scan -> row_ptr/col -----
__global__ __launch_bounds__(512) void binB_kernel(const unsigned* __restrict__ packed,
                                                   const int* __restrict__ cursor0,
                                                   int* __restrict__ row_ptr,
                                                   float* __restrict__ inv_deg,
                                                   int* __restrict__ col, int n, int ne) {
    __shared__ int sdeg[512];
    __shared__ int scur[512];
    __shared__ int scnt[NB_BUCKET];
    __shared__ int sebeg[NB_BUCKET];
    __shared__ int swv[8];
    int b = blockIdx.x, t = threadIdx.x;
    int lane = t & 63, wid = t >> 6;
    if (t < NB_BUCKET) scnt[t] = cursor0[t];
    sdeg[t] = 0;
    __syncthreads();
    if (t == 0) {                 // serial 98-scan (cheap, per-block)
        int run = 0;
        for (int i = 0; i < NB_BUCKET; ++i) { sebeg[i] = run; run += scnt[i]; }
    }
    __syncthreads();
    int ebeg = sebeg[b];
    int cntE = scnt[b];
    const unsigned* pk = packed + (size_t)b * BCAP;
    for (int e = t; e < cntE; e += 512) atomicAdd(&sdeg[pk[e] >> 16], 1);
    __syncthreads();
    int v = sdeg[t];
    int incl = v;                 // wave-level inclusive scan
#pragma unroll
    for (int d = 1; d < 64; d <<= 1) {
        int u = __shfl_up(incl, d, 64);
        if (lane >= d) incl += u;
    }
    if (lane == 63) swv[wid] = incl;
    __syncthreads();
    int wbase = 0;
    for (int i = 0; i < 8; ++i) wbase += (i < wid) ? swv[i] : 0;
    int excl = wbase + incl - v;
    scur[t] = excl;
    int node = (b << BSHIFT) + t;
    if (node < n) {
        row_ptr[node] = ebeg + excl;
        inv_deg[node] = 1.0f / (float)(v > 0 ? v : 1);
    }
    if (b == 0 && t == 0) row_ptr[n] = ne;
    __syncthreads();
    for (int e = t; e < cntE; e += 512) {
        unsigned w = pk[e];
        int dl = w >> 16;
        int pos = ebeg + atomicAdd(&scur[dl], 1);
        col[pos] = (int)(w & 0xffffu);
    }
}

// ---------------- mean aggregation over bf16, fp32 accumulate, bf16 out ------
// One wave per node (max TLP for the latency-bound gather — R11 lesson).
__global__ __launch_bounds__(256) void agg_kernel(const unsigned short* __restrict__ hb,
                                                  const int* __restrict__ row_ptr,
                                                  const int* __restrict__ col,
                                                  const float* __restrict__ inv_deg,
                                                  unsigned short* __restrict__ outb, int n) {
    int node = blockIdx.x * 4 + (threadIdx.x >> 6);
    if (node >= n) return;
    int lane = threadIdx.x & 63;
    int slot = lane >> 4, sub = lane & 15;
    int beg = row_ptr[node], end = row_ptr[node + 1];
    const unsigned short* base = hb + (sub << 3);
    float acc[8];
#pragma unroll
    for (int j = 0; j < 8; ++j) acc[j] = 0.f;

    int e = beg + slot;
    for (; e + 4 < end; e += 8) {
        int j0 = col[e];
        int j1 = col[e + 4];
        uint4 v0 = *(const uint4*)(base + ((size_t)j0 << 7));
        uint4 v1 = *(const uint4*)(base + ((size_t)j1 << 7));
        unsigned w0[4] = {v0.x, v0.y, v0.z, v0.w};
        unsigned w1[4] = {v1.x, v1.y, v1.z, v1.w};
#pragma unroll
        for (int d = 0; d < 4; ++d) {
            acc[2 * d + 0] += __uint_as_float(w0[d] << 16);
            acc[2 * d + 1] += __uint_as_float(w0[d] & 0xffff0000u);
            acc[2 * d + 0] += __uint_as_float(w1[d] << 16);
            acc[2 * d + 1] += __uint_as_float(w1[d] & 0xffff0000u);
        }
    }
    if (e < end) {
        int j0 = col[e];
        uint4 v0 = *(const uint4*)(base + ((size_t)j0 << 7));
        unsigned w0[4] = {v0.x, v0.y, v0.z, v0.w};
#pragma unroll
        for (int d = 0; d < 4; ++d) {
            acc[2 * d + 0] += __uint_as_float(w0[d] << 16);
            acc[2 * d + 1] += __uint_as_float(w0[d] & 0xffff0000u);
        }
    }
#pragma unroll
    for (int j = 0; j < 8; ++j) {
        acc[j] += __shfl_xor(acc[j], 16, 64);
        acc[j] += __shfl_xor(acc[j], 32, 64);
    }
    if (slot == 0) {
        float s = inv_deg[node];
        short8 o;
#pragma unroll
        for (int j = 0; j < 8; ++j) o[j] = (short)bf16_rne(acc[j] * s);
        *(short8*)(outb + ((size_t)node << 7) + (sub << 3)) = o;
    }
}

// ---- dual GEMM, swapped-operand MFMA (W as A, features as B) (+opt FC) -----
// D[hid][node]: col=lane&15=node, row=quad*4+reg=hid -> each lane's 4 acc regs
// are 4 consecutive hids of one node -> 8B coalesced short4v stores.
__global__ __launch_bounds__(256) void gemm_mfma(const unsigned short* __restrict__ A0b,
                                                 const unsigned short* __restrict__ A1b,
                                                 const short* __restrict__ Wf0,
                                                 const short* __restrict__ Wf1,
                                                 const float* __restrict__ bias,
                                                 unsigned short* __restrict__ outb,
                                                 const float* __restrict__ Wfc,
                                                 const float* __restrict__ bfc,
                                                 float* __restrict__ fcout,
                                                 int n) {
    int lane = threadIdx.x & 63;
    int wave = threadIdx.x >> 6;
    int quad = lane >> 4, m16 = lane & 15;
    int row_base = blockIdx.x * 64 + wave * 16;
    int arow = row_base + m16;
    if (arow > n - 1) arow = n - 1;            // clamp (padding rows never stored)

    f32x4 acc[8];
#pragma unroll
    for (int nt = 0; nt < 8; ++nt) acc[nt] = (f32x4){0.f, 0.f, 0.f, 0.f};

    const unsigned short* ap0 = A0b + ((size_t)arow << 7) + (quad << 3);
    const unsigned short* ap1 = A1b + ((size_t)arow << 7) + (quad << 3);
#pragma unroll
    for (int kc = 0; kc < 4; ++kc) {
        short8 a0 = *(const short8*)(ap0 + kc * 32);
        short8 a1 = *(const short8*)(ap1 + kc * 32);
        const short* wp0 = Wf0 + ((size_t)kc * 2 * 64 + lane) * 8;
        const short* wp1 = Wf1 + ((size_t)kc * 2 * 64 + lane) * 8;
#pragma unroll
        for (int nt = 0; nt < 8; ++nt) {
            short8 bh0 = *(const short8*)(wp0 + (size_t)nt * 4096);
            short8 bl0 = *(const short8*)(wp0 + (size_t)nt * 4096 + 512);
            short8 bh1 = *(const short8*)(wp1 + (size_t)nt * 4096);
            short8 bl1 = *(const short8*)(wp1 + (size_t)nt * 4096 + 512);
            acc[nt] = __builtin_amdgcn_mfma_f32_16x16x32_bf16(bh0, a0, acc[nt], 0, 0, 0);
            acc[nt] = __builtin_amdgcn_mfma_f32_16x16x32_bf16(bl0, a0, acc[nt], 0, 0, 0);
            acc[nt] = __builtin_amdgcn_mfma_f32_16x16x32_bf16(bh1, a1, acc[nt], 0, 0, 0);
            acc[nt] = __builtin_amdgcn_mfma_f32_16x16x32_bf16(bl1, a1, acc[nt], 0, 0, 0);
        }
    }

    // epilogue: lane owns node (row_base+m16), hids nt*16 + quad*4 + (0..3)
    int onode = row_base + m16;
    if (outb) {
        if (onode < n) {
            unsigned short* op = outb + ((size_t)onode << 7) + (quad << 2);
#pragma unroll
            for (int nt = 0; nt < 8; ++nt) {
                float4 bs = *(const float4*)(bias + nt * 16 + (quad << 2));
                short4v o;
                o[0] = (short)bf16_rne(fmaxf(acc[nt][0] + bs.x, 0.f));
                o[1] = (short)bf16_rne(fmaxf(acc[nt][1] + bs.y, 0.f));
                o[2] = (short)bf16_rne(fmaxf(acc[nt][2] + bs.z, 0.f));
                o[3] = (short)bf16_rne(fmaxf(acc[nt][3] + bs.w, 0.f));
                *(short4v*)(op + nt * 16) = o;
            }
        }
    } else {
        // fused FC: lane holds 32 hids of its node; reduce over 4 quad groups
        float p0 = 0.f, p1 = 0.f;
#pragma unroll
        for (int nt = 0; nt < 8; ++nt) {
            float4 bs = *(const float4*)(bias + nt * 16 + (quad << 2));
            float bv[4] = {bs.x, bs.y, bs.z, bs.w};
#pragma unroll
            for (int r = 0; r < 4; ++r) {
                float v = fmaxf(acc[nt][r] + bv[r], 0.f);
                int hid = nt * 16 + (quad << 2) + r;
                float2 wv = *(const float2*)(Wfc + 2 * hid);
                p0 += v * wv.x;
                p1 += v * wv.y;
            }
        }
        p0 += __shfl_xor(p0, 16, 64);
        p0 += __shfl_xor(p0, 32, 64);
        p1 += __shfl_xor(p1, 16, 64);
        p1 += __shfl_xor(p1, 32, 64);
        if (quad == 0 && onode < n) {
            float2 o;
            o.x = p0 + bfc[0];
            o.y = p1 + bfc[1];
            *(float2*)(fcout + 2 * (size_t)onode) = o;
        }
    }
}

extern "C" void kernel_launch(void* const* d_in, const int* in_sizes, int n_in,
                              void* d_out, int out_size, void* d_ws, size_t ws_size,
                              hipStream_t stream) {
    const float* x   = (const float*)d_in[0];
    const int* edge  = (const int*)d_in[1];
    const float* W1l = (const float*)d_in[2];
    const float* W1r = (const float*)d_in[3];
    const float* b1  = (const float*)d_in[4];
    const float* W2l = (const float*)d_in[5];
    const float* W2r = (const float*)d_in[6];
    const float* b2  = (const float*)d_in[7];
    const float* Wfc = (const float*)d_in[8];
    const float* bfc = (const float*)d_in[9];
    float* out = (float*)d_out;

    const int n = NN, ne = NE;
    const int* src = edge;        // edge_index[0]
    const int* dst = edge + ne;   // edge_index[1]

    char* ws = (char*)d_ws;
    size_t off = 0;
    auto alloc = [&](size_t bytes) -> char* {
        char* p = ws + off;
        off = (off + bytes + 511) & ~(size_t)511;
        return p;
    };
    int* row_ptr     = (int*)alloc((size_t)(n + 1) * 4);
    float* invdeg    = (float*)alloc((size_t)n * 4);
    int* cursor0     = (int*)alloc((size_t)NB_BUCKET * 4);
    short* wf        = (short*)alloc((size_t)4 * 32768 * 2);
    unsigned* packed = (unsigned*)alloc((size_t)NB_BUCKET * BCAP * 4);
    int* col         = (int*)alloc((size_t)ne * 4);
    unsigned short* aggb = (unsigned short*)alloc((size_t)n * 128 * 2);
    unsigned short* xb   = (unsigned short*)alloc((size_t)n * 128 * 2);
    unsigned short* h1b  = (unsigned short*)alloc((size_t)n * 128 * 2);
    (void)ws_size; (void)in_sizes; (void)n_in; (void)out_size;

    setup_kernel<<<SETUP_GRID, 256, 0, stream>>>(x, xb, W1l, W1r, W2l, W2r, wf, cursor0);
    binA_kernel<<<NBLK_E, 256, 0, stream>>>(src, dst, cursor0, packed, ne);
    binB_kernel<<<NB_BUCKET, 512, 0, stream>>>(packed, cursor0, row_ptr, invdeg, col, n, ne);

    agg_kernel<<<(n + 3) / 4, 256, 0, stream>>>(xb, row_ptr, col, invdeg, aggb, n);
    gemm_mfma<<<(n + 63) / 64, 256, 0, stream>>>(aggb, xb, wf, wf + 32768, b1, h1b,
                                                 (const float*)0, (const float*)0, (float*)0, n);
    agg_kernel<<<(n + 3) / 4, 256, 0, stream>>>(h1b, row_ptr, col, invdeg, aggb, n);
    gemm_mfma<<<(n + 63) / 64, 256, 0, stream>>>(aggb, h1b, wf + 2 * 32768, wf + 3 * 32768, b2,
                                                 (unsigned short*)0, Wfc, bfc, out, n);
}